// Round 5
// baseline (477.192 us; speedup 1.0000x reference)
//
#include <hip/hip_runtime.h>
#include <hip/hip_bf16.h>
#include <math.h>

typedef __hip_bfloat16 bf16;
typedef __attribute__((ext_vector_type(8))) short short8;   // 8 bf16 = 4 VGPRs
typedef __attribute__((ext_vector_type(4))) float f32x4;

#define DEV __device__ __forceinline__

// problem constants
constexpr int CB = 8, CN = 1024, CD = 768, CH = 12, CK = 64, CF = 3072;
constexpr int ROWS = CB * CN;  // 8192

// ---------------------------------------------------------------- utilities
DEV void gload_lds16(const void* g, void* l) {
  __builtin_amdgcn_global_load_lds(
      (const __attribute__((address_space(1))) void*)g,
      (__attribute__((address_space(3))) void*)l, 16, 0, 0);
}

// ------------------------------------------------------- weight prep (T + cast)
// in[R][C] fp32  ->  out[C][R] bf16, optionally scaled
__global__ __launch_bounds__(256) void transpose_f32_bf16(
    const float* __restrict__ in, bf16* __restrict__ out, int R, int C,
    float scale) {
  __shared__ float tile[32][33];
  const int tx = threadIdx.x & 31, ty = threadIdx.x >> 5;  // 32 x 8
  const int c0 = blockIdx.x * 32, r0 = blockIdx.y * 32;
#pragma unroll
  for (int i = 0; i < 4; ++i)
    tile[ty + i * 8][tx] = in[(size_t)(r0 + ty + i * 8) * C + c0 + tx];
  __syncthreads();
#pragma unroll
  for (int i = 0; i < 4; ++i)
    out[(size_t)(c0 + ty + i * 8) * R + r0 + tx] =
        __float2bfloat16(tile[tx][ty + i * 8] * scale);
}

// ---------------------------------------------------------------- LayerNorm
__global__ __launch_bounds__(256) void ln_bf16(
    const float* __restrict__ in, const float* __restrict__ gamma,
    const float* __restrict__ beta, bf16* __restrict__ out) {
  const int row = blockIdx.x;
  const int tid = threadIdx.x;
  const float* x = in + (size_t)row * CD;
  const float v0 = x[tid], v1 = x[tid + 256], v2 = x[tid + 512];
  float s = v0 + v1 + v2;
  float q = v0 * v0 + v1 * v1 + v2 * v2;
#pragma unroll
  for (int off = 32; off > 0; off >>= 1) {
    s += __shfl_xor(s, off);
    q += __shfl_xor(q, off);
  }
  __shared__ float sm[8];
  const int w = tid >> 6, l = tid & 63;
  if (l == 0) { sm[w] = s; sm[4 + w] = q; }
  __syncthreads();
  s = sm[0] + sm[1] + sm[2] + sm[3];
  q = sm[4] + sm[5] + sm[6] + sm[7];
  const float mean = s * (1.f / CD);
  const float var = q * (1.f / CD) - mean * mean;
  const float rs = rsqrtf(var + 1e-5f);
  bf16* o = out + (size_t)row * CD;
  o[tid]       = __float2bfloat16((v0 - mean) * rs * gamma[tid]       + beta[tid]);
  o[tid + 256] = __float2bfloat16((v1 - mean) * rs * gamma[tid + 256] + beta[tid + 256]);
  o[tid + 512] = __float2bfloat16((v2 - mean) * rs * gamma[tid + 512] + beta[tid + 512]);
}

// ---------------------------------------------------------------- GEMM
// C[M,N] = A[M,K] * Bt[N,K]^T  (both bf16, fp32 accum), 128x128 tile, BK=32,
// 4 waves (2x2). 1D grid with XCD swizzle (T1): hardware block L -> logical
// tile g = (L&7)*cpx + L>>3, row-major decode. Each XCD gets a contiguous
// row-major range -> A panels + B panel L2-resident per XCD.
// EPI 0: QKV (V blocks use swapped MFMA operands -> coalesced Vt store).
// EPI 1: +bias +resid, fp32 out. EPI 2: +bias, exact GELU, bf16 (ld=CF).
template <int EPI>
__global__ __launch_bounds__(256) void gemm_bf16_kernel(
    const bf16* __restrict__ A, const bf16* __restrict__ Bt, int Kd, int nbx,
    float* __restrict__ outF, bf16* __restrict__ dst0, bf16* __restrict__ dst1,
    bf16* __restrict__ dst2, const float* __restrict__ bias0,
    const float* __restrict__ bias1, const float* __restrict__ bias2,
    const float* __restrict__ resid) {
  __shared__ __align__(16) bf16 As[128 * 32];
  __shared__ __align__(16) bf16 Bs[128 * 32];
  const int tid = threadIdx.x;
  const int w = tid >> 6, l = tid & 63;
  const int wr = w >> 1, wc = w & 1;
  const int l15 = l & 15, lg = l >> 4;
  const int L = blockIdx.x;
  const int cpx = gridDim.x >> 3;
  const int g = (L & 7) * cpx + (L >> 3);
  const int by = g / nbx, bx = g - by * nbx;
  const int rowBase = by * 128;
  const int colBase = bx * 128;
  const bool vswap = (EPI == 0) && (colBase >= 2 * CD);

  f32x4 acc[4][4];
#pragma unroll
  for (int i = 0; i < 4; ++i)
#pragma unroll
    for (int j = 0; j < 4; ++j)
#pragma unroll
      for (int r = 0; r < 4; ++r) acc[i][j][r] = 0.f;

  for (int k0 = 0; k0 < Kd; k0 += 32) {
    __syncthreads();
#pragma unroll
    for (int i = 0; i < 2; ++i) {
      const int c = w * 128 + i * 64 + l;       // 16B chunk id, 0..511
      const int r = c >> 2, cc = c & 3;         // tile row, 8-elem col chunk
      gload_lds16(A + (size_t)(rowBase + r) * Kd + k0 + cc * 8,
                  (void*)&As[(w * 128 + i * 64) * 8]);
      gload_lds16(Bt + (size_t)(colBase + r) * Kd + k0 + cc * 8,
                  (void*)&Bs[(w * 128 + i * 64) * 8]);
    }
    __syncthreads();
    short8 af[4], bfr[4];
#pragma unroll
    for (int fm = 0; fm < 4; ++fm)
      af[fm] = *reinterpret_cast<const short8*>(
          &As[(wr * 64 + fm * 16 + l15) * 32 + lg * 8]);
#pragma unroll
    for (int fn = 0; fn < 4; ++fn)
      bfr[fn] = *reinterpret_cast<const short8*>(
          &Bs[(wc * 64 + fn * 16 + l15) * 32 + lg * 8]);
    if (vswap) {
#pragma unroll
      for (int fm = 0; fm < 4; ++fm)
#pragma unroll
        for (int fn = 0; fn < 4; ++fn)
          acc[fm][fn] = __builtin_amdgcn_mfma_f32_16x16x32_bf16(
              bfr[fn], af[fm], acc[fm][fn], 0, 0, 0);
    } else {
#pragma unroll
      for (int fm = 0; fm < 4; ++fm)
#pragma unroll
        for (int fn = 0; fn < 4; ++fn)
          acc[fm][fn] = __builtin_amdgcn_mfma_f32_16x16x32_bf16(
              af[fm], bfr[fn], acc[fm][fn], 0, 0, 0);
    }
  }

  const int mrow0 = rowBase + wr * 64;
  const int ncol0 = colBase + wc * 64;
  if constexpr (EPI == 0) {
    if (vswap) {
      // acc[fm][fn][fr] = V[n][hk]: n = mrow0+fm*16+l15 (lane axis),
      // hk = (ncol0-1536)+fn*16+lg*4+fr (reg axis) -> coalesced Vt store
#pragma unroll
      for (int fm = 0; fm < 4; ++fm) {
        const int n = mrow0 + fm * 16 + l15;
        const int b = n >> 10, nn = n & 1023;
#pragma unroll
        for (int fn = 0; fn < 4; ++fn) {
#pragma unroll
          for (int fr = 0; fr < 4; ++fr) {
            const int hk = (ncol0 - 2 * CD) + fn * 16 + lg * 4 + fr;
            const float v = acc[fm][fn][fr] + bias2[hk];
            const int h = hk >> 6, kk = hk & 63;
            dst2[((size_t)(b * CH + h) * CK + kk) * CN + nn] = __float2bfloat16(v);
          }
        }
      }
    } else {
#pragma unroll
      for (int fm = 0; fm < 4; ++fm) {
#pragma unroll
        for (int fn = 0; fn < 4; ++fn) {
          const int col = ncol0 + fn * 16 + l15;
          const int which = col / CD;  // 0=q 1=k
          const int hk = col - which * CD;
          const float bias = (which == 0) ? bias0[hk] * 0.125f : bias1[hk];
          bf16* dst = (which == 0) ? dst0 : dst1;
          const int h = hk >> 6, kk = hk & 63;
#pragma unroll
          for (int fr = 0; fr < 4; ++fr) {
            const int row = mrow0 + fm * 16 + lg * 4 + fr;
            const int b = row >> 10, n = row & 1023;
            dst[(((size_t)(b * CH + h)) * CN + n) * CK + kk] =
                __float2bfloat16(acc[fm][fn][fr] + bias);
          }
        }
      }
    }
  } else {
#pragma unroll
    for (int fm = 0; fm < 4; ++fm) {
#pragma unroll
      for (int fn = 0; fn < 4; ++fn) {
        const int col = ncol0 + fn * 16 + l15;
#pragma unroll
        for (int fr = 0; fr < 4; ++fr) {
          const int row = mrow0 + fm * 16 + lg * 4 + fr;
          float v = acc[fm][fn][fr];
          if constexpr (EPI == 1) {
            v += bias0[col] + resid[(size_t)row * CD + col];
            outF[(size_t)row * CD + col] = v;
          } else {  // EPI == 2: exact GELU -> bf16, ld = CF
            v += bias0[col];
            const float gel = 0.5f * v * (1.0f + erff(v * 0.70710678118654752f));
            dst0[(size_t)row * CF + col] = __float2bfloat16(gel);
          }
        }
      }
    }
  }
}

// ---------------------------------------------------------------- attention
// Streaming flash attention, zero barriers, TLP-first: wave owns 16 q-rows,
// grid = 1536 (head XCD-affinity: bh=(i&7)+8*(i>>7), qb=(i>>3)&15 -> all 16
// q-blocks of a head on one XCD; K/V 3MB/XCD L2-resident, proven R4).
// __launch_bounds__(256,4): 4 waves/SIMD to hide the serial chain.
// Swapped QK^T (S^T = mfma(K,Q)) -> 16 lane-local scores; defer-max (T13);
// per-lane partial lsum (end-reduced: saves 2 shfl/tile).
// Q pre-scaled by 1/8. Q,K: [B,H,N,64]; Vt: [B,H,64,N]; ctx: [B,N,H*64].
__global__ __launch_bounds__(256, 4) void attn_kernel(
    const bf16* __restrict__ Qb, const bf16* __restrict__ Kb,
    const bf16* __restrict__ Vtb, bf16* __restrict__ ctxb) {
  __shared__ __align__(16) bf16 Ps[4][16][72];  // per-wave P tile [q][k]

  const int tid = threadIdx.x;
  const int w = tid >> 6, l = tid & 63;
  const int l15 = l & 15, lg = l >> 4;
  const int i = blockIdx.x;
  const int bh = (i & 7) + 8 * (i >> 7);  // head 0..95, fixed per XCD
  const int qb = (i >> 3) & 15;           // 64-row q block
  const int b = bh / CH, h = bh - b * CH;
  const bf16* Qh  = Qb  + (size_t)bh * CN * CK;
  const bf16* Kh  = Kb  + (size_t)bh * CN * CK;
  const bf16* Vth = Vtb + (size_t)bh * CK * CN;
  const int q0 = qb * 64 + w * 16;

  // Q fragments held for the whole pass
  short8 aq[2];
#pragma unroll
  for (int c = 0; c < 2; ++c)
    aq[c] = *reinterpret_cast<const short8*>(
        Qh + (size_t)(q0 + l15) * CK + c * 32 + lg * 8);

  f32x4 oacc[4];
  float mreg = -INFINITY, lpart = 0.f;
#pragma unroll
  for (int kb = 0; kb < 4; ++kb)
#pragma unroll
    for (int r = 0; r < 4; ++r) oacc[kb][r] = 0.f;

#pragma unroll 1
  for (int kt = 0; kt < 16; ++kt) {
    // stream K and Vt fragments (L2-hit after first block on this XCD)
    const bf16* kbase = Kh + (size_t)kt * 64 * CK;
    const bf16* vbase = Vth + (size_t)kt * 64;
    short8 kf[4][2], vf[4][2];
#pragma unroll
    for (int mb = 0; mb < 4; ++mb)
#pragma unroll
      for (int c = 0; c < 2; ++c)
        kf[mb][c] = *reinterpret_cast<const short8*>(
            kbase + (size_t)(mb * 16 + l15) * CK + c * 32 + lg * 8);
#pragma unroll
    for (int kb = 0; kb < 4; ++kb)
#pragma unroll
      for (int c = 0; c < 2; ++c)
        vf[kb][c] = *reinterpret_cast<const short8*>(
            vbase + (size_t)(kb * 16 + l15) * CN + c * 32 + lg * 8);

    // S^T[k][q]: lane holds k = mb*16+lg*4+r for q = q0+l15
    f32x4 sacc[4];
    __builtin_amdgcn_s_setprio(1);
#pragma unroll
    for (int mb = 0; mb < 4; ++mb) {
      f32x4 z;
#pragma unroll
      for (int r = 0; r < 4; ++r) z[r] = 0.f;
      z = __builtin_amdgcn_mfma_f32_16x16x32_bf16(kf[mb][0], aq[0], z, 0, 0, 0);
      z = __builtin_amdgcn_mfma_f32_16x16x32_bf16(kf[mb][1], aq[1], z, 0, 0, 0);
      sacc[mb] = z;
    }
    __builtin_amdgcn_s_setprio(0);

    // row max: 16 lane-local + 2 shuffles
    float mx = sacc[0][0];
#pragma unroll
    for (int mb = 0; mb < 4; ++mb)
#pragma unroll
      for (int r = 0; r < 4; ++r) mx = fmaxf(mx, sacc[mb][r]);
    mx = fmaxf(mx, __shfl_xor(mx, 16));
    mx = fmaxf(mx, __shfl_xor(mx, 32));
    // defer-max: rescale only when max grew by > 8 (P bounded by e^8)
    if (!__all(mx - mreg <= 8.f)) {
      const float mn = fmaxf(mreg, mx);
      const float alpha = __expf(mreg - mn);
      float alr[4];
#pragma unroll
      for (int r = 0; r < 4; ++r) alr[r] = __shfl(alpha, lg * 4 + r);
#pragma unroll
      for (int kb = 0; kb < 4; ++kb)
#pragma unroll
        for (int r = 0; r < 4; ++r) oacc[kb][r] *= alr[r];
      lpart *= alpha;
      mreg = mn;
    }
#pragma unroll
    for (int mb = 0; mb < 4; ++mb)
#pragma unroll
      for (int r = 0; r < 4; ++r) {
        const float p = __expf(sacc[mb][r] - mreg);
        sacc[mb][r] = p;
        lpart += p;  // per-lane partial; reduced once at the end
      }

    // P^T -> Ps[w] (per-wave, intra-wave ordering, no barrier)
#pragma unroll
    for (int mb = 0; mb < 4; ++mb) {
      bf16 tmp[4];
#pragma unroll
      for (int r = 0; r < 4; ++r) tmp[r] = __float2bfloat16(sacc[mb][r]);
      *reinterpret_cast<uint2*>(&Ps[w][l15][mb * 16 + lg * 4]) =
          *reinterpret_cast<const uint2*>(tmp);
    }
    const short8 pa0 = *reinterpret_cast<const short8*>(&Ps[w][l15][lg * 8]);
    const short8 pa1 = *reinterpret_cast<const short8*>(&Ps[w][l15][32 + lg * 8]);

    __builtin_amdgcn_s_setprio(1);
#pragma unroll
    for (int kb = 0; kb < 4; ++kb) {
      oacc[kb] = __builtin_amdgcn_mfma_f32_16x16x32_bf16(pa0, vf[kb][0],
                                                         oacc[kb], 0, 0, 0);
      oacc[kb] = __builtin_amdgcn_mfma_f32_16x16x32_bf16(pa1, vf[kb][1],
                                                         oacc[kb], 0, 0, 0);
    }
    __builtin_amdgcn_s_setprio(0);
  }

  // reduce per-lane partial sums to per-row lsum (all 4 lg groups)
  float lsum = lpart;
  lsum += __shfl_xor(lsum, 16);
  lsum += __shfl_xor(lsum, 32);

  // finalize: ctx[b][n=q][h*64+d], O[q=lg*4+r][d=kb*16+l15]
#pragma unroll
  for (int r = 0; r < 4; ++r) {
    const float inv = 1.f / __shfl(lsum, lg * 4 + r);
    const int n = q0 + lg * 4 + r;
    bf16* dst = ctxb + ((size_t)(b * CN + n)) * CD + h * CK;
#pragma unroll
    for (int kb = 0; kb < 4; ++kb)
      dst[kb * 16 + l15] = __float2bfloat16(oacc[kb][r] * inv);
  }
}

// ---------------------------------------------------------------- launcher
// ws arena (bytes):
//   0         wqkvt  bf16 [2304][768]
//   3538944   wot    bf16 [768][768]
//   4718592   w1t    bf16 [3072][768]
//   9437184   w2t    bf16 [768][3072]
//   14155776  h1     bf16 [8192][768]   } reused as g bf16 [8192][3072]
//   26738688  Q      bf16 [B,H,N,K]     }
//   39321600  K      bf16 [B,H,N,K]     }
//   51904512  Vt     bf16 [B,H,K,N]     }
//   64487424  ctx    bf16 [8192][768]   -> reused as h2
//   77070336  out    f32  [8192][768]
extern "C" void kernel_launch(void* const* d_in, const int* in_sizes, int n_in,
                              void* d_out, int out_size, void* d_ws,
                              size_t ws_size, hipStream_t stream) {
  const float* x    = (const float*)d_in[0];
  const float* ln1g = (const float*)d_in[1];
  const float* ln1b = (const float*)d_in[2];
  const float* wq   = (const float*)d_in[3];
  const float* bq   = (const float*)d_in[4];
  const float* wk   = (const float*)d_in[5];
  const float* bk   = (const float*)d_in[6];
  const float* wv   = (const float*)d_in[7];
  const float* bv   = (const float*)d_in[8];
  const float* wo   = (const float*)d_in[9];
  const float* bo   = (const float*)d_in[10];
  const float* ln2g = (const float*)d_in[11];
  const float* ln2b = (const float*)d_in[12];
  const float* w1   = (const float*)d_in[13];
  const float* b1   = (const float*)d_in[14];
  const float* w2   = (const float*)d_in[15];
  const float* b2   = (const float*)d_in[16];

  char* ws = (char*)d_ws;
  bf16* wqkvt = (bf16*)(ws + 0);
  bf16* wot   = (bf16*)(ws + 3538944);
  bf16* w1t   = (bf16*)(ws + 4718592);
  bf16* w2t   = (bf16*)(ws + 9437184);
  bf16* h1    = (bf16*)(ws + 14155776);
  bf16* Qbuf  = (bf16*)(ws + 26738688);
  bf16* Kbuf  = (bf16*)(ws + 39321600);
  bf16* Vtbuf = (bf16*)(ws + 51904512);
  bf16* gb    = (bf16*)(ws + 14155776);  // reuse h1+Q+K+V region
  bf16* ctxb  = (bf16*)(ws + 64487424);
  bf16* h2    = (bf16*)(ws + 64487424);  // reuse ctx region
  float* outb = (float*)(ws + 77070336);
  float* y    = (float*)d_out;

  // weight prep: fp32 [R][C] -> bf16 [C][R]; wq pre-scaled by 1/sqrt(K)=1/8
  transpose_f32_bf16<<<dim3(24, 24), 256, 0, stream>>>(wq, wqkvt, 768, 768, 0.125f);
  transpose_f32_bf16<<<dim3(24, 24), 256, 0, stream>>>(wk, wqkvt + 768 * 768, 768, 768, 1.f);
  transpose_f32_bf16<<<dim3(24, 24), 256, 0, stream>>>(wv, wqkvt + 2 * 768 * 768, 768, 768, 1.f);
  transpose_f32_bf16<<<dim3(24, 24), 256, 0, stream>>>(wo, wot, 768, 768, 1.f);
  transpose_f32_bf16<<<dim3(96, 24), 256, 0, stream>>>(w1, w1t, 768, 3072, 1.f);
  transpose_f32_bf16<<<dim3(24, 96), 256, 0, stream>>>(w2, w2t, 3072, 768, 1.f);

  ln_bf16<<<ROWS, 256, 0, stream>>>(x, ln1g, ln1b, h1);

  gemm_bf16_kernel<0><<<18 * (ROWS / 128), 256, 0, stream>>>(
      h1, wqkvt, 768, 18, nullptr, Qbuf, Kbuf, Vtbuf, bq, bk, bv, nullptr);

  attn_kernel<<<CB * CH * 16, 256, 0, stream>>>(Qbuf, Kbuf, Vtbuf, ctxb);

  gemm_bf16_kernel<1><<<6 * (ROWS / 128), 256, 0, stream>>>(
      ctxb, wot, 768, 6, outb, nullptr, nullptr, nullptr, bo, nullptr, nullptr, x);

  ln_bf16<<<ROWS, 256, 0, stream>>>(outb, ln2g, ln2b, h2);

  gemm_bf16_kernel<2><<<24 * (ROWS / 128), 256, 0, stream>>>(
      h2, w1t, 768, 24, nullptr, gb, nullptr, nullptr, b1, nullptr, nullptr, nullptr);

  gemm_bf16_kernel<1><<<6 * (ROWS / 128), 256, 0, stream>>>(
      gb, w2t, 3072, 6, y, nullptr, nullptr, nullptr, b2, nullptr, nullptr, outb);

  (void)in_sizes; (void)n_in; (void)out_size; (void)ws_size;
}

// Round 7
// 373.888 us; speedup vs baseline: 1.2763x; 1.2763x over previous
//
#include <hip/hip_runtime.h>
#include <hip/hip_bf16.h>
#include <math.h>

typedef __hip_bfloat16 bf16;
typedef __attribute__((ext_vector_type(8))) short short8;   // 8 bf16 = 4 VGPRs
typedef __attribute__((ext_vector_type(4))) float f32x4;

#define DEV __device__ __forceinline__

// problem constants
constexpr int CB = 8, CN = 1024, CD = 768, CH = 12, CK = 64, CF = 3072;
constexpr int ROWS = CB * CN;  // 8192

// ---------------------------------------------------------------- utilities
DEV void gload_lds16(const void* g, void* l) {
  __builtin_amdgcn_global_load_lds(
      (const __attribute__((address_space(1))) void*)g,
      (__attribute__((address_space(3))) void*)l, 16, 0, 0);
}

// ------------------------------------------------------- weight prep (T + cast)
__global__ __launch_bounds__(256) void transpose_f32_bf16(
    const float* __restrict__ in, bf16* __restrict__ out, int R, int C,
    float scale) {
  __shared__ float tile[32][33];
  const int tx = threadIdx.x & 31, ty = threadIdx.x >> 5;  // 32 x 8
  const int c0 = blockIdx.x * 32, r0 = blockIdx.y * 32;
#pragma unroll
  for (int i = 0; i < 4; ++i)
    tile[ty + i * 8][tx] = in[(size_t)(r0 + ty + i * 8) * C + c0 + tx];
  __syncthreads();
#pragma unroll
  for (int i = 0; i < 4; ++i)
    out[(size_t)(c0 + ty + i * 8) * R + r0 + tx] =
        __float2bfloat16(tile[tx][ty + i * 8] * scale);
}

// ---------------------------------------------------------------- LayerNorm
__global__ __launch_bounds__(256) void ln_bf16(
    const float* __restrict__ in, const float* __restrict__ gamma,
    const float* __restrict__ beta, bf16* __restrict__ out) {
  const int row = blockIdx.x;
  const int tid = threadIdx.x;
  const float* x = in + (size_t)row * CD;
  const float v0 = x[tid], v1 = x[tid + 256], v2 = x[tid + 512];
  float s = v0 + v1 + v2;
  float q = v0 * v0 + v1 * v1 + v2 * v2;
#pragma unroll
  for (int off = 32; off > 0; off >>= 1) {
    s += __shfl_xor(s, off);
    q += __shfl_xor(q, off);
  }
  __shared__ float sm[8];
  const int w = tid >> 6, l = tid & 63;
  if (l == 0) { sm[w] = s; sm[4 + w] = q; }
  __syncthreads();
  s = sm[0] + sm[1] + sm[2] + sm[3];
  q = sm[4] + sm[5] + sm[6] + sm[7];
  const float mean = s * (1.f / CD);
  const float var = q * (1.f / CD) - mean * mean;
  const float rs = rsqrtf(var + 1e-5f);
  bf16* o = out + (size_t)row * CD;
  o[tid]       = __float2bfloat16((v0 - mean) * rs * gamma[tid]       + beta[tid]);
  o[tid + 256] = __float2bfloat16((v1 - mean) * rs * gamma[tid + 256] + beta[tid + 256]);
  o[tid + 512] = __float2bfloat16((v2 - mean) * rs * gamma[tid + 512] + beta[tid + 512]);
}

// ------------------------------------------- 256x256 8-phase GEMM (T2-T5)
// C[M,N] = A[M,K]*Bt[N,K]^T, BM=BN=256, BK=64, 512 threads = 8 waves (2Mx4N),
// per-wave 128x64 (acc[8][4]). LDS 128 KiB: As/Bs[2buf][2half][128x64].
// RACE-FREE stage schedule (derived from read-liveness, fixes R6):
//   B frags cached at phase 0 -> tile t's B regions dead after ph0 barrier;
//   A quad p read at phase p -> A regions dead at t's end.
//   tile t stages: ph0 (t+1,Ah0) ph1 (t+1,Ah1)   [other buf, always safe]
//                  ph2 (t+2,Bh0) ph3 (t+2,Bh1)   [cur buf, B dead since ph0]
//   vmcnt(4) at ph3 (steady): confirms through (t+1,Ah1) -> tile t+1 fully
//   landed; leaves (t+2,B*) = 4 loads in flight. t==NT-2: vmcnt(0). Prologue:
//   (0,A0)(0,A1)(0,B0)(0,B1)(1,B0)(1,B1) + vmcnt(4).
// T2 swizzle: LDS 16B-slot c16 ^= row&7 via inverse-swizzled GLOBAL source
// (gload_lds writes linearly, rule #21) + swizzled ds_read.
// EPI 0: QKV scatter (+bias; V col-tiles use swapped MFMA operands ->
//        coalesced Vt store; wq/bq pre-scaled 1/8). EPI 2: +bias, GELU, bf16.
template <int EPI>
__global__ __launch_bounds__(512, 2) void gemm256_kernel(
    const bf16* __restrict__ A, const bf16* __restrict__ Bt, int Kd, int nbx,
    bf16* __restrict__ dst0, bf16* __restrict__ dst1, bf16* __restrict__ dst2,
    const float* __restrict__ bias0, const float* __restrict__ bias1,
    const float* __restrict__ bias2) {
  __shared__ __align__(16) bf16 As[2][2][128 * 64];  // 64 KB
  __shared__ __align__(16) bf16 Bs[2][2][128 * 64];  // 64 KB

  const int tid = threadIdx.x;
  const int w = tid >> 6, l = tid & 63;
  const int wr = w >> 2, wc = w & 3;  // 2 x 4 wave grid
  const int l15 = l & 15, lg = l >> 4;

  const int L = blockIdx.x;
  const int cpx = gridDim.x >> 3;
  const int g = (L & 7) * cpx + (L >> 3);   // XCD swizzle (grid % 8 == 0)
  const int by = g / nbx, bx = g - by * nbx;
  const int rowBase = by * 256, colBase = bx * 256;
  const bool vswap = (EPI == 0) && (colBase >= 2 * CD);
  const int NT = Kd >> 6;

  // stage half-tile q (0:A-h0, 1:A-h1, 2:B-h0, 3:B-h1) of K-tile t
  auto stage = [&](int t, int q) {
    const int buf = t & 1;
    const int half = q & 1;
    const bf16* src = (q < 2) ? A : Bt;
    const int base = ((q < 2) ? rowBase : colBase) + half * 128;
    const int k0 = t * 64;
    bf16* lds = (q < 2) ? &As[buf][half][0] : &Bs[buf][half][0];
#pragma unroll
    for (int i = 0; i < 2; ++i) {
      const int s = i * 512 + tid;           // 16B slot 0..1023
      const int row = s >> 3, c16 = s & 7;
      const int gc16 = c16 ^ (row & 7);      // inverse swizzle on source
      gload_lds16(src + (size_t)(base + row) * Kd + k0 + gc16 * 8,
                  (void*)&lds[(i * 512 + w * 64) * 8]);
    }
  };
  auto read_a = [&](int buf, int m, int kh) -> short8 {
    const int row = m * 16 + l15;
    const int c16 = (kh * 4 + lg) ^ (l15 & 7);  // swizzled read
    return *reinterpret_cast<const short8*>(&As[buf][wr][row * 64 + c16 * 8]);
  };
  auto read_b = [&](int buf, int n, int kh) -> short8 {
    const int c = wc * 64 + n * 16 + l15;
    const int half = c >> 7, row = c & 127;
    const int c16 = (kh * 4 + lg) ^ (l15 & 7);
    return *reinterpret_cast<const short8*>(&Bs[buf][half][row * 64 + c16 * 8]);
  };

  f32x4 acc[8][4];
#pragma unroll
  for (int m = 0; m < 8; ++m)
#pragma unroll
    for (int n = 0; n < 4; ++n)
#pragma unroll
      for (int r = 0; r < 4; ++r) acc[m][n][r] = 0.f;

  // prologue (NT >= 2 always here: K=768 -> NT=12)
  stage(0, 0); stage(0, 1); stage(0, 2); stage(0, 3);
  stage(1, 2); stage(1, 3);
  asm volatile("s_waitcnt vmcnt(4)" ::: "memory");  // tile0 landed; (1,B*) in flight
  __builtin_amdgcn_s_barrier();

  short8 bfrag[4][2];
  for (int t = 0; t < NT; ++t) {
    const int buf = t & 1;
#pragma unroll
    for (int p = 0; p < 4; ++p) {
      short8 afr[2][2];
      if (p == 0) {
#pragma unroll
        for (int n = 0; n < 4; ++n)
#pragma unroll
          for (int kh = 0; kh < 2; ++kh) bfrag[n][kh] = read_b(buf, n, kh);
      }
#pragma unroll
      for (int mm = 0; mm < 2; ++mm)
#pragma unroll
        for (int kh = 0; kh < 2; ++kh) afr[mm][kh] = read_a(buf, 2 * p + mm, kh);
      // race-free stage slots (see header comment)
      if (p == 0 && t + 1 < NT) stage(t + 1, 0);
      if (p == 1 && t + 1 < NT) stage(t + 1, 1);
      if (p == 2 && t + 2 < NT) stage(t + 2, 2);
      if (p == 3 && t + 2 < NT) stage(t + 2, 3);
      __builtin_amdgcn_s_barrier();
      __builtin_amdgcn_s_setprio(1);
      if (!vswap) {
#pragma unroll
        for (int kh = 0; kh < 2; ++kh)
#pragma unroll
          for (int mm = 0; mm < 2; ++mm)
#pragma unroll
            for (int n = 0; n < 4; ++n)
              acc[2 * p + mm][n] = __builtin_amdgcn_mfma_f32_16x16x32_bf16(
                  afr[mm][kh], bfrag[n][kh], acc[2 * p + mm][n], 0, 0, 0);
      } else {
#pragma unroll
        for (int kh = 0; kh < 2; ++kh)
#pragma unroll
          for (int mm = 0; mm < 2; ++mm)
#pragma unroll
            for (int n = 0; n < 4; ++n)
              acc[2 * p + mm][n] = __builtin_amdgcn_mfma_f32_16x16x32_bf16(
                  bfrag[n][kh], afr[mm][kh], acc[2 * p + mm][n], 0, 0, 0);
      }
      __builtin_amdgcn_s_setprio(0);
      if (p == 3) {
        if (t < NT - 2)       asm volatile("s_waitcnt vmcnt(4)" ::: "memory");
        else if (t == NT - 2) asm volatile("s_waitcnt vmcnt(0)" ::: "memory");
        __builtin_amdgcn_sched_barrier(0);
      }
      __builtin_amdgcn_s_barrier();
    }
  }

  // epilogue: row = rowBase + wr*128 + m*16 + lg*4 + fr (reg axis),
  //           col = colBase + wc*64 + n*16 + l15      (lane axis)
  if constexpr (EPI == 0) {
    if (vswap) {
      // swapped: lane axis = token row, reg axis = hk col
#pragma unroll
      for (int m = 0; m < 8; ++m) {
        const int nrow = rowBase + wr * 128 + m * 16 + l15;
        const int b = nrow >> 10, nn = nrow & 1023;
#pragma unroll
        for (int n = 0; n < 4; ++n) {
#pragma unroll
          for (int fr = 0; fr < 4; ++fr) {
            const int hk = (colBase - 2 * CD) + wc * 64 + n * 16 + lg * 4 + fr;
            const float v = acc[m][n][fr] + bias2[hk];
            const int h = hk >> 6, kk = hk & 63;
            dst2[((size_t)(b * CH + h) * CK + kk) * CN + nn] = __float2bfloat16(v);
          }
        }
      }
    } else {
      const int which = colBase / CD;  // 0=Q, 1=K (256-tiles never straddle)
#pragma unroll
      for (int m = 0; m < 8; ++m) {
#pragma unroll
        for (int n = 0; n < 4; ++n) {
          const int col = colBase + wc * 64 + n * 16 + l15;
          const int hk = col - which * CD;
          const float bias = (which == 0) ? bias0[hk] * 0.125f : bias1[hk];
          bf16* dst = (which == 0) ? dst0 : dst1;
          const int h = hk >> 6, kk = hk & 63;
#pragma unroll
          for (int fr = 0; fr < 4; ++fr) {
            const int row = rowBase + wr * 128 + m * 16 + lg * 4 + fr;
            const int b = row >> 10, nn = row & 1023;
            dst[(((size_t)(b * CH + h)) * CN + nn) * CK + kk] =
                __float2bfloat16(acc[m][n][fr] + bias);
          }
        }
      }
    }
  } else {  // EPI == 2: +bias, exact GELU -> bf16 [*, CF]
#pragma unroll
    for (int m = 0; m < 8; ++m) {
#pragma unroll
      for (int n = 0; n < 4; ++n) {
        const int col = colBase + wc * 64 + n * 16 + l15;
        const float bias = bias0[col];
#pragma unroll
        for (int fr = 0; fr < 4; ++fr) {
          const int row = rowBase + wr * 128 + m * 16 + lg * 4 + fr;
          const float v = acc[m][n][fr] + bias;
          const float gel = 0.5f * v * (1.0f + erff(v * 0.70710678118654752f));
          dst0[(size_t)row * CF + col] = __float2bfloat16(gel);
        }
      }
    }
  }
}

// ---------------------------------------------------------------- GEMM 128²
// (m97 structure, for the narrow N=768 GEMMs where 256² underfills CUs)
// 1D grid with XCD swizzle. EPI 1: +bias +resid, fp32 out (ld=CD).
template <int EPI>
__global__ __launch_bounds__(256) void gemm_bf16_kernel(
    const bf16* __restrict__ A, const bf16* __restrict__ Bt, int Kd, int nbx,
    float* __restrict__ outF, const float* __restrict__ bias0,
    const float* __restrict__ resid) {
  __shared__ __align__(16) bf16 As[128 * 32];
  __shared__ __align__(16) bf16 Bs[128 * 32];
  const int tid = threadIdx.x;
  const int w = tid >> 6, l = tid & 63;
  const int wr = w >> 1, wc = w & 1;
  const int l15 = l & 15, lg = l >> 4;
  const int L = blockIdx.x;
  const int cpx = gridDim.x >> 3;
  const int g = (L & 7) * cpx + (L >> 3);
  const int by = g / nbx, bx = g - by * nbx;
  const int rowBase = by * 128;
  const int colBase = bx * 128;

  f32x4 acc[4][4];
#pragma unroll
  for (int i = 0; i < 4; ++i)
#pragma unroll
    for (int j = 0; j < 4; ++j)
#pragma unroll
      for (int r = 0; r < 4; ++r) acc[i][j][r] = 0.f;

  for (int k0 = 0; k0 < Kd; k0 += 32) {
    __syncthreads();
#pragma unroll
    for (int i = 0; i < 2; ++i) {
      const int c = w * 128 + i * 64 + l;
      const int r = c >> 2, cc = c & 3;
      gload_lds16(A + (size_t)(rowBase + r) * Kd + k0 + cc * 8,
                  (void*)&As[(w * 128 + i * 64) * 8]);
      gload_lds16(Bt + (size_t)(colBase + r) * Kd + k0 + cc * 8,
                  (void*)&Bs[(w * 128 + i * 64) * 8]);
    }
    __syncthreads();
    short8 af[4], bfr[4];
#pragma unroll
    for (int fm = 0; fm < 4; ++fm)
      af[fm] = *reinterpret_cast<const short8*>(
          &As[(wr * 64 + fm * 16 + l15) * 32 + lg * 8]);
#pragma unroll
    for (int fn = 0; fn < 4; ++fn)
      bfr[fn] = *reinterpret_cast<const short8*>(
          &Bs[(wc * 64 + fn * 16 + l15) * 32 + lg * 8]);
#pragma unroll
    for (int fm = 0; fm < 4; ++fm)
#pragma unroll
      for (int fn = 0; fn < 4; ++fn)
        acc[fm][fn] = __builtin_amdgcn_mfma_f32_16x16x32_bf16(
            af[fm], bfr[fn], acc[fm][fn], 0, 0, 0);
  }

  const int mrow0 = rowBase + wr * 64;
  const int ncol0 = colBase + wc * 64;
#pragma unroll
  for (int fm = 0; fm < 4; ++fm) {
#pragma unroll
    for (int fn = 0; fn < 4; ++fn) {
      const int col = ncol0 + fn * 16 + l15;
#pragma unroll
      for (int fr = 0; fr < 4; ++fr) {
        const int row = mrow0 + fm * 16 + lg * 4 + fr;
        float v = acc[fm][fn][fr];
        v += bias0[col] + resid[(size_t)row * CD + col];
        outF[(size_t)row * CD + col] = v;
      }
    }
  }
}

// ---------------------------------------------------------------- attention
// R4 version (97.6 µs): zero barriers, reg dbuf K/V prefetch, head XCD
// affinity (bh=(i&7)+8*(i>>6), qb=(i>>3)&7 -> K/V L2-resident per XCD),
// swapped QK^T, defer-max. Q pre-scaled 1/8.
__global__ __launch_bounds__(256, 2) void attn_kernel(
    const bf16* __restrict__ Qb, const bf16* __restrict__ Kb,
    const bf16* __restrict__ Vtb, bf16* __restrict__ ctxb) {
  __shared__ __align__(16) bf16 Ps[4][16][72];

  const int tid = threadIdx.x;
  const int w = tid >> 6, l = tid & 63;
  const int l15 = l & 15, lg = l >> 4;
  const int i = blockIdx.x;
  const int bh = (i & 7) + 8 * (i >> 6);
  const int qb = (i >> 3) & 7;
  const int b = bh / CH, h = bh - b * CH;
  const bf16* Qh  = Qb  + (size_t)bh * CN * CK;
  const bf16* Kh  = Kb  + (size_t)bh * CN * CK;
  const bf16* Vth = Vtb + (size_t)bh * CK * CN;
  const int q0 = qb * 128 + w * 32;

  short8 aq[2][2];
#pragma unroll
  for (int s = 0; s < 2; ++s)
#pragma unroll
    for (int c = 0; c < 2; ++c)
      aq[s][c] = *reinterpret_cast<const short8*>(
          Qh + (size_t)(q0 + s * 16 + l15) * CK + c * 32 + lg * 8);

  f32x4 oacc[2][4];
  float mreg[2], lsum[2];
#pragma unroll
  for (int s = 0; s < 2; ++s) {
    mreg[s] = -INFINITY;
    lsum[s] = 0.f;
#pragma unroll
    for (int kb = 0; kb < 4; ++kb)
#pragma unroll
      for (int r = 0; r < 4; ++r) oacc[s][kb][r] = 0.f;
  }

  auto load_kv = [&](short8 (&kf)[4][2], short8 (&vf)[4][2], int kt) {
    const bf16* kbase = Kh + (size_t)kt * 64 * CK;
#pragma unroll
    for (int mb = 0; mb < 4; ++mb)
#pragma unroll
      for (int c = 0; c < 2; ++c)
        kf[mb][c] = *reinterpret_cast<const short8*>(
            kbase + (size_t)(mb * 16 + l15) * CK + c * 32 + lg * 8);
    const bf16* vbase = Vth + (size_t)kt * 64;
#pragma unroll
    for (int kb = 0; kb < 4; ++kb)
#pragma unroll
      for (int c = 0; c < 2; ++c)
        vf[kb][c] = *reinterpret_cast<const short8*>(
            vbase + (size_t)(kb * 16 + l15) * CN + c * 32 + lg * 8);
  };

  auto compute_tile = [&](short8 (&kf)[4][2], short8 (&vf)[4][2]) {
#pragma unroll
    for (int s = 0; s < 2; ++s) {
      f32x4 sacc[4];
      __builtin_amdgcn_s_setprio(1);
#pragma unroll
      for (int mb = 0; mb < 4; ++mb) {
        f32x4 z;
#pragma unroll
        for (int r = 0; r < 4; ++r) z[r] = 0.f;
        z = __builtin_amdgcn_mfma_f32_16x16x32_bf16(kf[mb][0], aq[s][0], z, 0, 0, 0);
        z = __builtin_amdgcn_mfma_f32_16x16x32_bf16(kf[mb][1], aq[s][1], z, 0, 0, 0);
        sacc[mb] = z;
      }
      __builtin_amdgcn_s_setprio(0);
      float mx = sacc[0][0];
#pragma unroll
      for (int mb = 0; mb < 4; ++mb)
#pragma unroll
        for (int r = 0; r < 4; ++r) mx = fmaxf(mx, sacc[mb][r]);
      mx = fmaxf(mx, __shfl_xor(mx, 16));
      mx = fmaxf(mx, __shfl_xor(mx, 32));
      if (!__all(mx - mreg[s] <= 8.f)) {
        const float mn = fmaxf(mreg[s], mx);
        const float alpha = __expf(mreg[s] - mn);
        float alr[4];
#pragma unroll
        for (int r = 0; r < 4; ++r) alr[r] = __shfl(alpha, lg * 4 + r);
#pragma unroll
        for (int kb = 0; kb < 4; ++kb)
#pragma unroll
          for (int r = 0; r < 4; ++r) oacc[s][kb][r] *= alr[r];
        lsum[s] *= alpha;
        mreg[s] = mn;
      }
      const float mnew = mreg[s];
      float rs = 0.f;
#pragma unroll
      for (int mb = 0; mb < 4; ++mb)
#pragma unroll
        for (int r = 0; r < 4; ++r) {
          const float p = __expf(sacc[mb][r] - mnew);
          sacc[mb][r] = p;
          rs += p;
        }
      rs += __shfl_xor(rs, 16);
      rs += __shfl_xor(rs, 32);
      lsum[s] += rs;

#pragma unroll
      for (int mb = 0; mb < 4; ++mb) {
        bf16 tmp[4];
#pragma unroll
        for (int r = 0; r < 4; ++r) tmp[r] = __float2bfloat16(sacc[mb][r]);
        *reinterpret_cast<uint2*>(&Ps[w][l15][mb * 16 + lg * 4]) =
            *reinterpret_cast<const uint2*>(tmp);
      }
      const short8 pa0 = *reinterpret_cast<const short8*>(&Ps[w][l15][lg * 8]);
      const short8 pa1 = *reinterpret_cast<const short8*>(&Ps[w][l15][32 + lg * 8]);

      __builtin_amdgcn_s_setprio(1);
#pragma unroll
      for (int kb = 0; kb < 4; ++kb) {
        oacc[s][kb] = __builtin_amdgcn_mfma_f32_16x16x32_bf16(pa0, vf[kb][0],
                                                              oacc[s][kb], 0, 0, 0);
        oacc[s][kb] = __builtin_amdgcn_mfma_f32_16x16x32_bf16(pa1, vf[kb][1],
                                                              oacc[s][kb], 0, 0, 0);
      }
      __builtin_amdgcn_s_setprio(0);
    }
  };

  short8 kfA[4][2], vfA[4][2], kfB[4][2], vfB[4][2];
  load_kv(kfA, vfA, 0);
#pragma unroll 1
  for (int p = 0; p < 7; ++p) {
    load_kv(kfB, vfB, 2 * p + 1);
    compute_tile(kfA, vfA);
    load_kv(kfA, vfA, 2 * p + 2);
    compute_tile(kfB, vfB);
  }
  load_kv(kfB, vfB, 15);
  compute_tile(kfA, vfA);
  compute_tile(kfB, vfB);

#pragma unroll
  for (int s = 0; s < 2; ++s) {
#pragma unroll
    for (int r = 0; r < 4; ++r) {
      const float inv = 1.f / __shfl(lsum[s], lg * 4 + r);
      const int n = q0 + s * 16 + lg * 4 + r;
      bf16* dst = ctxb + ((size_t)(b * CN + n)) * CD + h * CK;
#pragma unroll
      for (int kb = 0; kb < 4; ++kb)
        dst[kb * 16 + l15] = __float2bfloat16(oacc[s][kb][r] * inv);
    }
  }
}

// ---------------------------------------------------------------- launcher
extern "C" void kernel_launch(void* const* d_in, const int* in_sizes, int n_in,
                              void* d_out, int out_size, void* d_ws,
                              size_t ws_size, hipStream_t stream) {
  const float* x    = (const float*)d_in[0];
  const float* ln1g = (const float*)d_in[1];
  const float* ln1b = (const float*)d_in[2];
  const float* wq   = (const float*)d_in[3];
  const float* bq   = (const float*)d_in[4];
  const float* wk   = (const float*)d_in[5];
  const float* bk   = (const float*)d_in[6];
  const float* wv   = (const float*)d_in[7];
  const float* bv   = (const float*)d_in[8];
  const float* wo   = (const float*)d_in[9];
  const float* bo   = (const float*)d_in[10];
  const float* ln2g = (const float*)d_in[11];
  const float* ln2b = (const float*)d_in[12];
  const float* w1   = (const float*)d_in[13];
  const float* b1   = (const float*)d_in[14];
  const float* w2   = (const float*)d_in[15];
  const float* b2   = (const float*)d_in[16];

  char* ws = (char*)d_ws;
  bf16* wqkvt = (bf16*)(ws + 0);
  bf16* wot   = (bf16*)(ws + 3538944);
  bf16* w1t   = (bf16*)(ws + 4718592);
  bf16* w2t   = (bf16*)(ws + 9437184);
  bf16* h1    = (bf16*)(ws + 14155776);
  bf16* Qbuf  = (bf16*)(ws + 26738688);
  bf16* Kbuf  = (bf16*)(ws + 39321600);
  bf16* Vtbuf = (bf16*)(ws + 51904512);
  bf16* gb    = (bf16*)(ws + 14155776);  // reuse h1+Q+K+V region
  bf16* ctxb  = (bf16*)(ws + 64487424);
  bf16* h2    = (bf16*)(ws + 64487424);  // reuse ctx region
  float* outb = (float*)(ws + 77070336);
  float* y    = (float*)d_out;

  transpose_f32_bf16<<<dim3(24, 24), 256, 0, stream>>>(wq, wqkvt, 768, 768, 0.125f);
  transpose_f32_bf16<<<dim3(24, 24), 256, 0, stream>>>(wk, wqkvt + 768 * 768, 768, 768, 1.f);
  transpose_f32_bf16<<<dim3(24, 24), 256, 0, stream>>>(wv, wqkvt + 2 * 768 * 768, 768, 768, 1.f);
  transpose_f32_bf16<<<dim3(24, 24), 256, 0, stream>>>(wo, wot, 768, 768, 1.f);
  transpose_f32_bf16<<<dim3(96, 24), 256, 0, stream>>>(w1, w1t, 768, 3072, 1.f);
  transpose_f32_bf16<<<dim3(24, 96), 256, 0, stream>>>(w2, w2t, 3072, 768, 1.f);

  ln_bf16<<<ROWS, 256, 0, stream>>>(x, ln1g, ln1b, h1);

  // QKV: 256² 8-phase, grid 32x9 = 288 (%8==0)
  gemm256_kernel<0><<<(ROWS / 256) * 9, 512, 0, stream>>>(
      h1, wqkvt, 768, 9, Qbuf, Kbuf, Vtbuf, bq, bk, bv);

  attn_kernel<<<CB * CH * 8, 256, 0, stream>>>(Qbuf, Kbuf, Vtbuf, ctxb);

  gemm_bf16_kernel<1><<<6 * (ROWS / 128), 256, 0, stream>>>(
      ctxb, wot, 768, 6, outb, bo, x);

  ln_bf16<<<ROWS, 256, 0, stream>>>(outb, ln2g, ln2b, h2);

  // MLP1: 256² 8-phase, grid 32x12 = 384 (%8==0)
  gemm256_kernel<2><<<(ROWS / 256) * 12, 512, 0, stream>>>(
      h2, w1t, 768, 12, gb, nullptr, nullptr, b1, nullptr, nullptr);

  gemm_bf16_kernel<1><<<6 * (ROWS / 128), 256, 0, stream>>>(
      gb, w2t, 3072, 6, y, b2, outb);

  (void)in_sizes; (void)n_in; (void)out_size; (void)ws_size;
}